// Round 1
// baseline (198.943 us; speedup 1.0000x reference)
//
#include <hip/hip_runtime.h>
#include <math.h>

// Problem constants (from reference)
#define IN_DIM   512
#define OUT_DIM  512
#define KDEG     3
#define NUMG     16
#define BATCH    256
#define NB       19          // NUM + K  (final basis count)
#define NG       23          // NUM + 2K + 1 (grid points per row)
#define KAUG     20          // 19 spline slots + 1 base(silu) slot
#define KTOT     (IN_DIM * KAUG)   // 10240

// ---------------------------------------------------------------------------
// Kernel 1: build augmented A matrix  (BATCH x KTOT)
//   A[b][i*20 + g] = B_spline(x[b,i], grid[i])[g]   for g in [0,19)
//   A[b][i*20 + 19] = silu(x[b,i])
// One thread per (b,i).
// ---------------------------------------------------------------------------
__global__ void build_A(const float* __restrict__ X,
                        const float* __restrict__ G,
                        float* __restrict__ A) {
    int t = blockIdx.x * blockDim.x + threadIdx.x;   // 0 .. BATCH*IN_DIM-1
    if (t >= BATCH * IN_DIM) return;
    int b = t / IN_DIM;
    int i = t - b * IN_DIM;

    float x = X[t];

    float gr[NG];
    const float* g = G + i * NG;
#pragma unroll
    for (int j = 0; j < NG; j++) gr[j] = g[j];

    // order-0 basis: indicator of interval
    float B[NG - 1];
#pragma unroll
    for (int j = 0; j < NG - 1; j++)
        B[j] = (x >= gr[j] && x < gr[j + 1]) ? 1.0f : 0.0f;

    // Cox-de Boor recurrence, in-place (forward j uses old B[j+1])
#pragma unroll
    for (int kk = 1; kk <= KDEG; kk++) {
#pragma unroll
        for (int j = 0; j < NG - 1 - kk; j++) {
            float d1 = gr[j + kk] - gr[j];
            float d2 = gr[j + kk + 1] - gr[j + 1];
            B[j] = (x - gr[j]) / d1 * B[j] +
                   (gr[j + kk + 1] - x) / d2 * B[j + 1];
        }
    }

    float* a = A + (size_t)b * KTOT + i * KAUG;
#pragma unroll
    for (int j = 0; j < NB; j++) a[j] = B[j];
    a[NB] = x / (1.0f + __expf(-x));   // silu
}

// ---------------------------------------------------------------------------
// Kernel 2: build augmented W matrix  (KTOT x OUT_DIM), k-major, o contiguous
//   W[(i*20+g)][o] = coef[i][o][g] * scale_sp[i][o] * mask[i][o]  (g < 19)
//   W[(i*20+19)][o] = mask[i][o]
// grid = (KTOT, OUT_DIM/256), block = 256
// ---------------------------------------------------------------------------
__global__ void build_W(const float* __restrict__ coef,
                        const float* __restrict__ scale_sp,
                        const float* __restrict__ mask,
                        float* __restrict__ W) {
    int k = blockIdx.x;                            // 0 .. KTOT-1
    int o = blockIdx.y * blockDim.x + threadIdx.x; // 0 .. OUT_DIM-1
    int i = k / KAUG;
    int g = k - i * KAUG;
    int io = i * OUT_DIM + o;
    float m = mask[io];
    float v;
    if (g == NB) {
        v = m;
    } else {
        v = coef[(size_t)io * NB + g] * scale_sp[io] * m;
    }
    W[(size_t)k * OUT_DIM + o] = v;
}

// ---------------------------------------------------------------------------
// Kernel 3: split-K tiled fp32 GEMM:  out[b][o] += sum_k A[b][k] * W[k][o]
// Block tile 64x64, BK=16, 256 threads, 4x4 micro-tile per thread.
// grid = (OUT_DIM/64, BATCH/64, SPLITS); fp32 atomicAdd epilogue.
// ---------------------------------------------------------------------------
#define BM 64
#define BN 64
#define BK 16
#define SPLITS 8
#define KC (KTOT / SPLITS)   // 1280

__global__ __launch_bounds__(256) void gemm_splitk(const float* __restrict__ A,
                                                   const float* __restrict__ W,
                                                   float* __restrict__ out) {
    __shared__ float As[BK][BM];
    __shared__ float Ws[BK][BN];

    int tid = threadIdx.x;
    int m0 = blockIdx.y * BM;
    int n0 = blockIdx.x * BN;
    int kbase = blockIdx.z * KC;

    // A-tile load mapping: 64 rows x 16 k, float4 per thread along k
    int am = tid >> 2;          // 0..63
    int ak = (tid & 3) << 2;    // 0,4,8,12
    // W-tile load mapping: 16 k x 64 o, float4 per thread along o
    int wk = tid >> 4;          // 0..15
    int wn = (tid & 15) << 2;   // 0..60

    // compute mapping: 4x4 per thread
    int tm = (tid >> 4) << 2;   // 0..60
    int tn = (tid & 15) << 2;   // 0..60

    float acc[4][4] = {};

    for (int kk = 0; kk < KC; kk += BK) {
        float4 av = *(const float4*)(A + (size_t)(m0 + am) * KTOT + kbase + kk + ak);
        As[ak + 0][am] = av.x;
        As[ak + 1][am] = av.y;
        As[ak + 2][am] = av.z;
        As[ak + 3][am] = av.w;

        float4 wv = *(const float4*)(W + (size_t)(kbase + kk + wk) * OUT_DIM + n0 + wn);
        *(float4*)&Ws[wk][wn] = wv;

        __syncthreads();

#pragma unroll
        for (int k2 = 0; k2 < BK; k2++) {
            float a0 = As[k2][tm + 0];
            float a1 = As[k2][tm + 1];
            float a2 = As[k2][tm + 2];
            float a3 = As[k2][tm + 3];
            float w0 = Ws[k2][tn + 0];
            float w1 = Ws[k2][tn + 1];
            float w2 = Ws[k2][tn + 2];
            float w3 = Ws[k2][tn + 3];
            acc[0][0] += a0 * w0; acc[0][1] += a0 * w1; acc[0][2] += a0 * w2; acc[0][3] += a0 * w3;
            acc[1][0] += a1 * w0; acc[1][1] += a1 * w1; acc[1][2] += a1 * w2; acc[1][3] += a1 * w3;
            acc[2][0] += a2 * w0; acc[2][1] += a2 * w1; acc[2][2] += a2 * w2; acc[2][3] += a2 * w3;
            acc[3][0] += a3 * w0; acc[3][1] += a3 * w1; acc[3][2] += a3 * w2; acc[3][3] += a3 * w3;
        }

        __syncthreads();
    }

#pragma unroll
    for (int mi = 0; mi < 4; mi++) {
#pragma unroll
        for (int ni = 0; ni < 4; ni++) {
            atomicAdd(&out[(size_t)(m0 + tm + mi) * OUT_DIM + n0 + tn + ni],
                      acc[mi][ni]);
        }
    }
}

// ---------------------------------------------------------------------------
extern "C" void kernel_launch(void* const* d_in, const int* in_sizes, int n_in,
                              void* d_out, int out_size, void* d_ws, size_t ws_size,
                              hipStream_t stream) {
    const float* x        = (const float*)d_in[0];   // (256, 512)
    const float* grid     = (const float*)d_in[1];   // (512, 23)
    const float* coef     = (const float*)d_in[2];   // (512, 512, 19)
    const float* scale_sp = (const float*)d_in[3];   // (512, 512)
    const float* mask     = (const float*)d_in[4];   // (512, 512)
    float* out = (float*)d_out;                      // (256, 512)

    float* A = (float*)d_ws;                         // BATCH x KTOT   (10.5 MB)
    float* W = A + (size_t)BATCH * KTOT;             // KTOT x OUT_DIM (21 MB)

    // 1. build A
    build_A<<<dim3((BATCH * IN_DIM) / 256), dim3(256), 0, stream>>>(x, grid, A);

    // 2. build W
    build_W<<<dim3(KTOT, OUT_DIM / 256), dim3(256), 0, stream>>>(coef, scale_sp, mask, W);

    // 3. zero out, then split-K GEMM with atomic accumulation
    hipMemsetAsync(d_out, 0, (size_t)out_size * sizeof(float), stream);
    gemm_splitk<<<dim3(OUT_DIM / BN, BATCH / BM, SPLITS), dim3(256), 0, stream>>>(A, W, out);
}

// Round 2
// 110.905 us; speedup vs baseline: 1.7938x; 1.7938x over previous
//
#include <hip/hip_runtime.h>

// Problem constants
#define IN_DIM   512
#define OUT_DIM  512
#define KDEG     3
#define BATCH    256
#define NB       19                 // NUM + K  spline basis count
#define NG       23                 // grid points per input dim
#define KAUG     20                 // 19 spline slots + 1 base(silu) slot
#define KTOT     (IN_DIM * KAUG)    // 10240

typedef short  bf16x8 __attribute__((ext_vector_type(8)));   // 8 bf16 = 4 VGPRs
typedef float  f32x4  __attribute__((ext_vector_type(4)));

// round-to-nearest-even fp32 -> bf16 (no NaN inputs here)
__device__ __forceinline__ unsigned short f2bf(float f) {
    union { float f; unsigned int u; } v; v.f = f;
    unsigned int r = (v.u + 0x7FFF + ((v.u >> 16) & 1)) >> 16;
    return (unsigned short)r;
}

// async global->LDS, 16B per lane. lds dest must be wave-uniform; lane L's
// 16B lands at ldst + L*16 (guide §5 caveat). CK-style addrspace casts.
__device__ __forceinline__ void async_copy16(const void* gsrc, const void* ldst) {
    auto g = (const __attribute__((address_space(1))) unsigned int*)((unsigned long long)gsrc);
    auto l = (__attribute__((address_space(3))) unsigned int*)((unsigned int)(unsigned long long)ldst);
    __builtin_amdgcn_global_load_lds(g, l, 16, 0, 0);
}

// ---------------------------------------------------------------------------
// Kernel 1: augmented A (BATCH x KTOT), bf16, k-contiguous.
//   A[b][i*20+g] = Bspline_g(x[b,i]),  A[b][i*20+19] = silu(x[b,i])
// ---------------------------------------------------------------------------
__global__ void build_A(const float* __restrict__ X,
                        const float* __restrict__ G,
                        unsigned short* __restrict__ A) {
    int t = blockIdx.x * blockDim.x + threadIdx.x;
    if (t >= BATCH * IN_DIM) return;
    int b = t / IN_DIM;
    int i = t - b * IN_DIM;

    float x = X[t];

    float gr[NG];
    const float* g = G + i * NG;
#pragma unroll
    for (int j = 0; j < NG; j++) gr[j] = g[j];

    float B[NG - 1];
#pragma unroll
    for (int j = 0; j < NG - 1; j++)
        B[j] = (x >= gr[j] && x < gr[j + 1]) ? 1.0f : 0.0f;

#pragma unroll
    for (int kk = 1; kk <= KDEG; kk++) {
#pragma unroll
        for (int j = 0; j < NG - 1 - kk; j++) {
            float d1 = gr[j + kk] - gr[j];
            float d2 = gr[j + kk + 1] - gr[j + 1];
            B[j] = (x - gr[j]) / d1 * B[j] +
                   (gr[j + kk + 1] - x) / d2 * B[j + 1];
        }
    }

    unsigned short v[KAUG];
#pragma unroll
    for (int j = 0; j < NB; j++) v[j] = f2bf(B[j]);
    v[NB] = f2bf(x / (1.0f + __expf(-x)));   // silu

    // 40B contiguous store (10 dwords, 4B-aligned)
    unsigned int* dst = (unsigned int*)(A + (size_t)b * KTOT + i * KAUG);
    const unsigned int* src = (const unsigned int*)v;
#pragma unroll
    for (int d = 0; d < KAUG / 2; d++) dst[d] = src[d];
}

// ---------------------------------------------------------------------------
// Kernel 2: augmented W^T (OUT_DIM x KTOT), bf16, k-contiguous.
//   Wt[o][i*20+g] = coef[i][o][g]*scale[i][o]*mask[i][o]  (g<19)
//   Wt[o][i*20+19] = mask[i][o]
// Lanes sweep o => coef reads are contiguous 76B/lane (fully covered).
// ---------------------------------------------------------------------------
__global__ void build_Wt(const float* __restrict__ coef,
                         const float* __restrict__ scale_sp,
                         const float* __restrict__ mask,
                         unsigned short* __restrict__ Wt) {
    int t = blockIdx.x * blockDim.x + threadIdx.x;   // 0 .. 512*512-1
    int i = t >> 9;
    int o = t & 511;
    int io = i * OUT_DIM + o;
    float m  = mask[io];
    float sm = scale_sp[io] * m;
    const float* c = coef + (size_t)io * NB;

    unsigned short v[KAUG];
#pragma unroll
    for (int g = 0; g < NB; g++) v[g] = f2bf(c[g] * sm);
    v[NB] = f2bf(m);

    unsigned int* dst = (unsigned int*)(Wt + (size_t)o * KTOT + i * KAUG);
    const unsigned int* src = (const unsigned int*)v;
#pragma unroll
    for (int d = 0; d < KAUG / 2; d++) dst[d] = src[d];
}

// ---------------------------------------------------------------------------
// Kernel 3: bf16 MFMA split-K GEMM:  out[b][o] += A[b][:] . Wt[o][:]
// BM=128, BN=64, BK=32; 256 thr = 4 waves, each wave 64m x 32n (4x2 tiles).
// grid = (8, 2, 16); fp32 atomicAdd epilogue into zeroed out.
// ---------------------------------------------------------------------------
#define BM 128
#define BN 64
#define BK 32
#define SPLITS 16
#define KCH (KTOT / SPLITS)   // 640

__global__ __launch_bounds__(256) void gemm_mfma(const unsigned short* __restrict__ A,
                                                 const unsigned short* __restrict__ Wt,
                                                 float* __restrict__ out) {
    __shared__ __align__(16) unsigned short As[BM * BK];  // [m][k] 8KB
    __shared__ __align__(16) unsigned short Bs[BN * BK];  // [n][k] 4KB

    int tid  = threadIdx.x;
    int lane = tid & 63;
    int w    = tid >> 6;          // wave 0..3
    int wm   = w >> 1;            // m-half
    int wn   = w & 1;             // n-half
    int m0 = blockIdx.y * BM;
    int n0 = blockIdx.x * BN;
    int kbase = blockIdx.z * KCH;

    const unsigned short* Ablk = A  + (size_t)m0 * KTOT + kbase;
    const unsigned short* Bblk = Wt + (size_t)n0 * KTOT + kbase;

    f32x4 acc[4][2];
#pragma unroll
    for (int i = 0; i < 4; i++)
#pragma unroll
        for (int j = 0; j < 2; j++) acc[i][j] = (f32x4)0.0f;

    int quad = lane >> 4;
    int lr   = lane & 15;

    for (int kk = 0; kk < KCH; kk += BK) {
        // --- stage A (512 slots of 16B): slot s -> m=s>>2, koff=(s&3)*8
        {
            int s = w * 64 + lane;                       // issue 0
            async_copy16(Ablk + (size_t)(s >> 2) * KTOT + kk + (s & 3) * 8,
                         (const char*)As + (w * 64) * 16);
            s = 256 + w * 64 + lane;                     // issue 1
            async_copy16(Ablk + (size_t)(s >> 2) * KTOT + kk + (s & 3) * 8,
                         (const char*)As + (256 + w * 64) * 16);
        }
        // --- stage B (256 slots): slot s -> n=s>>2, koff=(s&3)*8
        {
            int s = w * 64 + lane;
            async_copy16(Bblk + (size_t)(s >> 2) * KTOT + kk + (s & 3) * 8,
                         (const char*)Bs + (w * 64) * 16);
        }
        __syncthreads();   // drains vmcnt (global_load_lds) + lgkmcnt

        // --- fragments: A[m=lane&15][k=quad*8+j], B[n=lane&15][k=quad*8+j]
        bf16x8 af[4], bfg[2];
#pragma unroll
        for (int mt = 0; mt < 4; mt++)
            af[mt] = *(const bf16x8*)&As[(wm * 64 + mt * 16 + lr) * BK + quad * 8];
#pragma unroll
        for (int nt = 0; nt < 2; nt++)
            bfg[nt] = *(const bf16x8*)&Bs[(wn * 32 + nt * 16 + lr) * BK + quad * 8];

#pragma unroll
        for (int mt = 0; mt < 4; mt++)
#pragma unroll
            for (int nt = 0; nt < 2; nt++)
                acc[mt][nt] = __builtin_amdgcn_mfma_f32_16x16x32_bf16(
                    af[mt], bfg[nt], acc[mt][nt], 0, 0, 0);

        __syncthreads();
    }

    // --- epilogue: C/D layout col=lane&15, row=quad*4+reg
#pragma unroll
    for (int mt = 0; mt < 4; mt++) {
#pragma unroll
        for (int nt = 0; nt < 2; nt++) {
            int col = n0 + wn * 32 + nt * 16 + lr;
            int rb  = m0 + wm * 64 + mt * 16 + quad * 4;
#pragma unroll
            for (int r = 0; r < 4; r++)
                atomicAdd(&out[(size_t)(rb + r) * OUT_DIM + col], acc[mt][nt][r]);
        }
    }
}

// ---------------------------------------------------------------------------
extern "C" void kernel_launch(void* const* d_in, const int* in_sizes, int n_in,
                              void* d_out, int out_size, void* d_ws, size_t ws_size,
                              hipStream_t stream) {
    const float* x        = (const float*)d_in[0];   // (256, 512)
    const float* grid     = (const float*)d_in[1];   // (512, 23)
    const float* coef     = (const float*)d_in[2];   // (512, 512, 19)
    const float* scale_sp = (const float*)d_in[3];   // (512, 512)
    const float* mask     = (const float*)d_in[4];   // (512, 512)
    float* out = (float*)d_out;                      // (256, 512)

    unsigned short* A  = (unsigned short*)d_ws;              // 5.24 MB
    unsigned short* Wt = A + (size_t)BATCH * KTOT;           // 10.49 MB

    build_A<<<dim3((BATCH * IN_DIM + 255) / 256), dim3(256), 0, stream>>>(x, grid, A);
    build_Wt<<<dim3((IN_DIM * OUT_DIM) / 256), dim3(256), 0, stream>>>(coef, scale_sp, mask, Wt);

    hipMemsetAsync(d_out, 0, (size_t)out_size * sizeof(float), stream);
    gemm_mfma<<<dim3(OUT_DIM / BN, BATCH / BM, SPLITS), dim3(256), 0, stream>>>(A, Wt, out);
}

// Round 3
// 101.530 us; speedup vs baseline: 1.9595x; 1.0923x over previous
//
#include <hip/hip_runtime.h>

// Problem constants
#define IN_DIM   512
#define OUT_DIM  512
#define KDEG     3
#define BATCH    256
#define NB       19                 // spline basis count per input dim
#define NG       23                 // grid points per input dim
#define KAUG     20                 // 19 spline slots + 1 base(silu) slot
#define KTOT     (IN_DIM * KAUG)    // 10240

typedef short  bf16x8 __attribute__((ext_vector_type(8)));   // 8 bf16 = 4 VGPRs
typedef float  f32x4  __attribute__((ext_vector_type(4)));

// round-to-nearest-even fp32 -> bf16
__device__ __forceinline__ unsigned short f2bf(float f) {
    union { float f; unsigned int u; } v; v.f = f;
    unsigned int r = (v.u + 0x7FFF + ((v.u >> 16) & 1)) >> 16;
    return (unsigned short)r;
}

// ---------------------------------------------------------------------------
// Kernel 1: augmented A (BATCH x KTOT), bf16, k-contiguous.
//   A[b][i*20+g] = Bspline_g(x[b,i]),  A[b][i*20+19] = silu(x[b,i])
// ---------------------------------------------------------------------------
__global__ void build_A(const float* __restrict__ X,
                        const float* __restrict__ G,
                        unsigned short* __restrict__ A) {
    int t = blockIdx.x * blockDim.x + threadIdx.x;
    if (t >= BATCH * IN_DIM) return;
    int b = t / IN_DIM;
    int i = t - b * IN_DIM;

    float x = X[t];

    float gr[NG];
    const float* g = G + i * NG;
#pragma unroll
    for (int j = 0; j < NG; j++) gr[j] = g[j];

    float B[NG - 1];
#pragma unroll
    for (int j = 0; j < NG - 1; j++)
        B[j] = (x >= gr[j] && x < gr[j + 1]) ? 1.0f : 0.0f;

#pragma unroll
    for (int kk = 1; kk <= KDEG; kk++) {
#pragma unroll
        for (int j = 0; j < NG - 1 - kk; j++) {
            float d1 = gr[j + kk] - gr[j];
            float d2 = gr[j + kk + 1] - gr[j + 1];
            B[j] = (x - gr[j]) / d1 * B[j] +
                   (gr[j + kk + 1] - x) / d2 * B[j + 1];
        }
    }

    unsigned short v[KAUG];
#pragma unroll
    for (int j = 0; j < NB; j++) v[j] = f2bf(B[j]);
    v[NB] = f2bf(x / (1.0f + __expf(-x)));   // silu

    unsigned int* dst = (unsigned int*)(A + (size_t)b * KTOT + i * KAUG);
    const unsigned int* src = (const unsigned int*)v;
#pragma unroll
    for (int d = 0; d < KAUG / 2; d++) dst[d] = src[d];
}

// ---------------------------------------------------------------------------
// Kernel 2 (fused W-build + GEMM):  out[b][o] += A[b][:] . W[:, o]
//   W[(i*20+g)][o] = coef[i][o][g]*scale[i][o]*mask[i][o];  W[i*20+19][o]=mask
// Grid = (16 o-blocks, 1, 16 k-splits), 512 threads = 8 waves.
// BM=256 (all of M, wave w owns rows [32w,32w+32)), BN=32, KCH=640 (32 i's).
// Each block converts its private (32i x 32o) coef slice into a bf16 LDS
// tile once (coef read exactly once from HBM), then runs a barrier-free
// fully-unrolled K-loop: A-frags from global, B-frags via ds_read_b128.
// fp32 atomicAdd epilogue into zeroed out.
// ---------------------------------------------------------------------------
#define BN     32
#define SPLITS 16
#define ICH    32                  // i's per block
#define KCH    (ICH * KAUG)        // 640
#define LDS_K  (KCH + 8)           // +8 elems (16B) pad: row stride 1296B,
                                   // 16B-aligned, banks 4n%32 -> 2-way max (free)

__global__ __launch_bounds__(512) void gemm_fused(const unsigned short* __restrict__ A,
                                                  const float* __restrict__ coef,
                                                  const float* __restrict__ scale_sp,
                                                  const float* __restrict__ mask,
                                                  float* __restrict__ out) {
    __shared__ __align__(16) unsigned short Bs[BN * LDS_K];   // 41472 B

    int tid = threadIdx.x;
    int o0 = blockIdx.x * BN;
    int i0 = blockIdx.z * ICH;
    int kbase = blockIdx.z * KCH;

    // ---- fill phase: 32i x 32o = 1024 (i,o) pairs, 2 per thread -----------
#pragma unroll
    for (int s = 0; s < 2; s++) {
        int p = tid + s * 512;
        int o = p & 31;            // lanes sweep o -> coalesced coef reads
        int di = p >> 5;
        int io = (i0 + di) * OUT_DIM + (o0 + o);
        float m  = mask[io];
        float sm = scale_sp[io] * m;
        const float* c = coef + (size_t)io * NB;

        __align__(8) unsigned short v[KAUG];
#pragma unroll
        for (int g = 0; g < NB; g++) v[g] = f2bf(c[g] * sm);
        v[NB] = f2bf(m);           // silu-slot weight

        // 40B contiguous at Bs[o][di*20], 8B-aligned -> 5x ds_write_b64
        unsigned long long* dst =
            (unsigned long long*)((char*)Bs + (size_t)o * (LDS_K * 2) + di * (KAUG * 2));
        const unsigned long long* src = (const unsigned long long*)v;
#pragma unroll
        for (int d = 0; d < 5; d++) dst[d] = src[d];
    }
    __syncthreads();               // the ONLY barrier

    // ---- compute phase: barrier-free unrolled K-loop ----------------------
    int lane = tid & 63;
    int w    = tid >> 6;           // wave 0..7, owns m-strip [32w, 32w+32)
    int quad = lane >> 4;
    int lr   = lane & 15;

    f32x4 acc[2][2];
#pragma unroll
    for (int i = 0; i < 2; i++)
#pragma unroll
        for (int j = 0; j < 2; j++) acc[i][j] = (f32x4)0.0f;

    // per-lane fragment base pointers (16B-aligned)
    const unsigned short* a0 = A + (size_t)(w * 32 + lr)      * KTOT + kbase + quad * 8;
    const unsigned short* a1 = A + (size_t)(w * 32 + 16 + lr) * KTOT + kbase + quad * 8;
    const unsigned short* b0 = &Bs[(size_t)lr        * LDS_K + quad * 8];
    const unsigned short* b1 = &Bs[(size_t)(16 + lr) * LDS_K + quad * 8];

#pragma unroll
    for (int kk = 0; kk < KCH; kk += 32) {
        bf16x8 af0 = *(const bf16x8*)(a0 + kk);
        bf16x8 af1 = *(const bf16x8*)(a1 + kk);
        bf16x8 bf0 = *(const bf16x8*)(b0 + kk);
        bf16x8 bf1 = *(const bf16x8*)(b1 + kk);
        acc[0][0] = __builtin_amdgcn_mfma_f32_16x16x32_bf16(af0, bf0, acc[0][0], 0, 0, 0);
        acc[0][1] = __builtin_amdgcn_mfma_f32_16x16x32_bf16(af0, bf1, acc[0][1], 0, 0, 0);
        acc[1][0] = __builtin_amdgcn_mfma_f32_16x16x32_bf16(af1, bf0, acc[1][0], 0, 0, 0);
        acc[1][1] = __builtin_amdgcn_mfma_f32_16x16x32_bf16(af1, bf1, acc[1][1], 0, 0, 0);
    }

    // ---- epilogue: C/D layout col=lane&15, row=quad*4+reg -----------------
#pragma unroll
    for (int mt = 0; mt < 2; mt++) {
#pragma unroll
        for (int nt = 0; nt < 2; nt++) {
            int col = o0 + nt * 16 + lr;
            int rb  = w * 32 + mt * 16 + quad * 4;
#pragma unroll
            for (int r = 0; r < 4; r++)
                atomicAdd(&out[(size_t)(rb + r) * OUT_DIM + col], acc[mt][nt][r]);
        }
    }
}

// ---------------------------------------------------------------------------
extern "C" void kernel_launch(void* const* d_in, const int* in_sizes, int n_in,
                              void* d_out, int out_size, void* d_ws, size_t ws_size,
                              hipStream_t stream) {
    const float* x        = (const float*)d_in[0];   // (256, 512)
    const float* grid     = (const float*)d_in[1];   // (512, 23)
    const float* coef     = (const float*)d_in[2];   // (512, 512, 19)
    const float* scale_sp = (const float*)d_in[3];   // (512, 512)
    const float* mask     = (const float*)d_in[4];   // (512, 512)
    float* out = (float*)d_out;                      // (256, 512)

    unsigned short* A = (unsigned short*)d_ws;       // 5.24 MB

    build_A<<<dim3((BATCH * IN_DIM + 255) / 256), dim3(256), 0, stream>>>(x, grid, A);

    hipMemsetAsync(d_out, 0, (size_t)out_size * sizeof(float), stream);
    gemm_fused<<<dim3(OUT_DIM / BN, 1, SPLITS), dim3(512), 0, stream>>>(
        A, coef, scale_sp, mask, out);
}

// Round 4
// 99.219 us; speedup vs baseline: 2.0051x; 1.0233x over previous
//
#include <hip/hip_runtime.h>

// Problem constants
#define IN_DIM   512
#define OUT_DIM  512
#define KDEG     3
#define BATCH    256
#define NB       19                 // spline basis count per input dim
#define NG       23                 // grid points per input dim
#define KAUG     20                 // 19 spline slots + 1 base(silu) slot
#define KTOT     (IN_DIM * KAUG)    // 10240

typedef short  bf16x8 __attribute__((ext_vector_type(8)));   // 8 bf16 = 4 VGPRs
typedef float  f32x4  __attribute__((ext_vector_type(4)));

// round-to-nearest-even fp32 -> bf16
__device__ __forceinline__ unsigned short f2bf(float f) {
    union { float f; unsigned int u; } v; v.f = f;
    unsigned int r = (v.u + 0x7FFF + ((v.u >> 16) & 1)) >> 16;
    return (unsigned short)r;
}

// ---------------------------------------------------------------------------
// Kernel 1: augmented A (BATCH x KTOT), bf16, k-contiguous.
//   A[b][i*20+g] = Bspline_g(x[b,i]),  A[b][i*20+19] = silu(x[b,i])
// ---------------------------------------------------------------------------
__global__ void build_A(const float* __restrict__ X,
                        const float* __restrict__ G,
                        unsigned short* __restrict__ A) {
    int t = blockIdx.x * blockDim.x + threadIdx.x;
    if (t >= BATCH * IN_DIM) return;
    int b = t / IN_DIM;
    int i = t - b * IN_DIM;

    float x = X[t];

    float gr[NG];
    const float* g = G + i * NG;
#pragma unroll
    for (int j = 0; j < NG; j++) gr[j] = g[j];

    float B[NG - 1];
#pragma unroll
    for (int j = 0; j < NG - 1; j++)
        B[j] = (x >= gr[j] && x < gr[j + 1]) ? 1.0f : 0.0f;

#pragma unroll
    for (int kk = 1; kk <= KDEG; kk++) {
#pragma unroll
        for (int j = 0; j < NG - 1 - kk; j++) {
            float d1 = gr[j + kk] - gr[j];
            float d2 = gr[j + kk + 1] - gr[j + 1];
            B[j] = (x - gr[j]) / d1 * B[j] +
                   (gr[j + kk + 1] - x) / d2 * B[j + 1];
        }
    }

    unsigned short v[KAUG];
#pragma unroll
    for (int j = 0; j < NB; j++) v[j] = f2bf(B[j]);
    v[NB] = f2bf(x / (1.0f + __expf(-x)));   // silu

    unsigned int* dst = (unsigned int*)(A + (size_t)b * KTOT + i * KAUG);
    const unsigned int* src = (const unsigned int*)v;
#pragma unroll
    for (int d = 0; d < KAUG / 2; d++) dst[d] = src[d];
}

// ---------------------------------------------------------------------------
// Kernel 2 (fused W-build + split-K GEMM -> fp32 partials):
//   P[z][b][o] = sum_{k in chunk z} A[b][k] * W[k][o]
//   W[(i*20+g)][o] = coef[i][o][g]*scale[i][o]*mask[i][o];  W[i*20+19][o]=mask
// Grid = (16 o-blocks, 1, 32 k-splits) = 512 blocks (2/CU, 16 waves/CU),
// 512 threads = 8 waves; BM=256 (wave w owns rows [32w,32w+32)), BN=32,
// ICH=16 i's -> KCH=320. coef read exactly once. Barrier-free 10-iter K-loop.
// ---------------------------------------------------------------------------
#define BN     32
#define SPLITS 32
#define ICH    16                  // i's per block
#define KCH    (ICH * KAUG)        // 320
#define LDS_K  (KCH + 8)           // 328 elems -> row stride 656B (8B-aligned)

__global__ __launch_bounds__(512, 4) void gemm_fused(
        const unsigned short* __restrict__ A,
        const float* __restrict__ coef,
        const float* __restrict__ scale_sp,
        const float* __restrict__ mask,
        float* __restrict__ P) {
    __shared__ __align__(16) unsigned short Bs[BN * LDS_K];   // 20992 B

    int tid = threadIdx.x;
    int o0 = blockIdx.x * BN;
    int i0 = blockIdx.z * ICH;
    int kbase = blockIdx.z * KCH;

    // ---- fill phase: 16i x 32o = 512 (i,o) pairs, 1 per thread ------------
    {
        int o  = tid & 31;         // lanes sweep o -> coalesced mask/scale
        int di = tid >> 5;         // 0..15
        int io = (i0 + di) * OUT_DIM + (o0 + o);
        float m  = mask[io];
        float sm = scale_sp[io] * m;
        const float* c = coef + (size_t)io * NB;

        __align__(8) unsigned short v[KAUG];
#pragma unroll
        for (int g = 0; g < NB; g++) v[g] = f2bf(c[g] * sm);
        v[NB] = f2bf(m);           // silu-slot weight

        unsigned long long* dst =
            (unsigned long long*)((char*)Bs + (size_t)o * (LDS_K * 2) + di * (KAUG * 2));
        const unsigned long long* src = (const unsigned long long*)v;
#pragma unroll
        for (int d = 0; d < 5; d++) dst[d] = src[d];
    }
    __syncthreads();               // the ONLY barrier

    // ---- compute phase: barrier-free unrolled K-loop ----------------------
    int lane = tid & 63;
    int w    = tid >> 6;           // wave 0..7, owns m-strip [32w, 32w+32)
    int quad = lane >> 4;
    int lr   = lane & 15;

    f32x4 acc[2][2];
#pragma unroll
    for (int i = 0; i < 2; i++)
#pragma unroll
        for (int j = 0; j < 2; j++) acc[i][j] = (f32x4)0.0f;

    const unsigned short* a0 = A + (size_t)(w * 32 + lr)      * KTOT + kbase + quad * 8;
    const unsigned short* a1 = A + (size_t)(w * 32 + 16 + lr) * KTOT + kbase + quad * 8;
    const unsigned short* b0 = &Bs[(size_t)lr        * LDS_K + quad * 8];
    const unsigned short* b1 = &Bs[(size_t)(16 + lr) * LDS_K + quad * 8];

#pragma unroll
    for (int kk = 0; kk < KCH; kk += 32) {
        bf16x8 af0 = *(const bf16x8*)(a0 + kk);
        bf16x8 af1 = *(const bf16x8*)(a1 + kk);
        bf16x8 bf0 = *(const bf16x8*)(b0 + kk);
        bf16x8 bf1 = *(const bf16x8*)(b1 + kk);
        acc[0][0] = __builtin_amdgcn_mfma_f32_16x16x32_bf16(af0, bf0, acc[0][0], 0, 0, 0);
        acc[0][1] = __builtin_amdgcn_mfma_f32_16x16x32_bf16(af0, bf1, acc[0][1], 0, 0, 0);
        acc[1][0] = __builtin_amdgcn_mfma_f32_16x16x32_bf16(af1, bf0, acc[1][0], 0, 0, 0);
        acc[1][1] = __builtin_amdgcn_mfma_f32_16x16x32_bf16(af1, bf1, acc[1][1], 0, 0, 0);
    }

    // ---- epilogue: plain coalesced stores into per-split partial buffer ---
    // C/D layout: col=lane&15, row=quad*4+reg
    float* Pz = P + (size_t)blockIdx.z * BATCH * OUT_DIM;
#pragma unroll
    for (int mt = 0; mt < 2; mt++) {
#pragma unroll
        for (int nt = 0; nt < 2; nt++) {
            int col = o0 + nt * 16 + lr;
            int rb  = w * 32 + mt * 16 + quad * 4;
#pragma unroll
            for (int r = 0; r < 4; r++)
                Pz[(size_t)(rb + r) * OUT_DIM + col] = acc[mt][nt][r];
        }
    }
}

// ---------------------------------------------------------------------------
// Kernel 3: reduce partials: out[e] = sum_z P[z][e], float4-vectorized.
// grid = 128 x 256 threads, one float4 per thread.
// ---------------------------------------------------------------------------
__global__ __launch_bounds__(256) void reduce_out(const float* __restrict__ P,
                                                  float* __restrict__ out) {
    int e4 = blockIdx.x * blockDim.x + threadIdx.x;   // 0 .. 32767
    f32x4 s = (f32x4)0.0f;
#pragma unroll
    for (int z = 0; z < SPLITS; z++) {
        f32x4 v = *(const f32x4*)(P + (size_t)z * BATCH * OUT_DIM + e4 * 4);
        s += v;
    }
    *(f32x4*)((float*)out + (size_t)e4 * 4) = s;
}

// ---------------------------------------------------------------------------
extern "C" void kernel_launch(void* const* d_in, const int* in_sizes, int n_in,
                              void* d_out, int out_size, void* d_ws, size_t ws_size,
                              hipStream_t stream) {
    const float* x        = (const float*)d_in[0];   // (256, 512)
    const float* grid     = (const float*)d_in[1];   // (512, 23)
    const float* coef     = (const float*)d_in[2];   // (512, 512, 19)
    const float* scale_sp = (const float*)d_in[3];   // (512, 512)
    const float* mask     = (const float*)d_in[4];   // (512, 512)
    float* out = (float*)d_out;                      // (256, 512)

    unsigned short* A = (unsigned short*)d_ws;                        // 5.24 MB
    float* P = (float*)((char*)d_ws + (size_t)BATCH * KTOT * 2);      // 16.8 MB

    build_A<<<dim3((BATCH * IN_DIM + 255) / 256), dim3(256), 0, stream>>>(x, grid, A);

    gemm_fused<<<dim3(OUT_DIM / BN, 1, SPLITS), dim3(512), 0, stream>>>(
        A, coef, scale_sp, mask, P);

    reduce_out<<<dim3(BATCH * OUT_DIM / 4 / 256), dim3(256), 0, stream>>>(P, out);
}